// Round 1
// baseline (1583.736 us; speedup 1.0000x reference)
//
#include <hip/hip_runtime.h>

typedef unsigned int u32;
typedef unsigned short u16;
typedef __bf16 bf16x8 __attribute__((ext_vector_type(8)));
typedef float f32x4 __attribute__((ext_vector_type(4)));
typedef unsigned short u16x4 __attribute__((ext_vector_type(4)));

#define AS1 __attribute__((address_space(1)))
#define AS3 __attribute__((address_space(3)))

// ---------- helpers ----------
static __device__ __forceinline__ u16 f2bf(float f) {
  u32 u = __builtin_bit_cast(u32, f);
  u32 r = (u + 0x7fffu + ((u >> 16) & 1u)) >> 16;  // RNE
  return (u16)r;
}

// ---------- f32 -> bf16 conversion (vectorized x4) ----------
__global__ void k_conv4(const float4* __restrict__ in, u16x4* __restrict__ out, int n4) {
  int i = blockIdx.x * 256 + threadIdx.x;
  if (i >= n4) return;
  float4 v = in[i];
  u16x4 o = { f2bf(v.x), f2bf(v.y), f2bf(v.z), f2bf(v.w) };
  out[i] = o;
}

// ---------- embedding gather -> bf16 [2048][512] ----------
__global__ void k_gather(const int* __restrict__ idx, const float* __restrict__ emb,
                         u16* __restrict__ x) {
  int row = blockIdx.x;              // b*128 + t
  int id = idx[row];
  const float4* src = (const float4*)(emb + (size_t)id * 512);
  u16x4* dst = (u16x4*)(x + (size_t)row * 512);
  int i = threadIdx.x;               // 128 threads, 4 floats each
  float4 v = src[i];
  u16x4 o = { f2bf(v.x), f2bf(v.y), f2bf(v.z), f2bf(v.w) };
  dst[i] = o;
}

// ---------- bf16 GEMM: C[M][N] = A[M][K] * B[N][K]^T + bias, f32 out ----------
// 128x128 tile, BK=64, 4 waves (2x2 of 64x64), XOR-swizzled LDS (st-16-style).
__global__ __launch_bounds__(256) void k_gemm_bt(
    const u16* __restrict__ A, int lda,
    const u16* __restrict__ Bm, int ldb,
    const float* __restrict__ bias,
    float* __restrict__ C, int ldc, int K) {
  __shared__ u16 sA[128 * 64];
  __shared__ u16 sB[128 * 64];
  const int tid = threadIdx.x;
  const int wv = tid >> 6, lane = tid & 63;
  const int row0 = blockIdx.x << 7, col0 = blockIdx.y << 7;
  const int wr = (wv >> 1) << 6, wc = (wv & 1) << 6;   // wave quadrant offsets
  const int lr = lane & 15;                // row within 16-tile
  const int lkb = (lane >> 4) << 4;        // k byte offset within 32-k step (16B groups)

  f32x4 acc[4][4];
#pragma unroll
  for (int mi = 0; mi < 4; ++mi)
#pragma unroll
    for (int ni = 0; ni < 4; ++ni) acc[mi][ni] = f32x4{0.f, 0.f, 0.f, 0.f};

  const int chunkc = (wv << 6) + lane;

  for (int kt = 0; kt < K; kt += 64) {
#pragma unroll
    for (int p = 0; p < 4; ++p) {
      int cbase = (p << 8) + (wv << 6);
      int c = cbase + lane;
      int r = c >> 3;
      int ks = ((c & 7) << 3) ^ ((r & 7) << 3);   // pre-swizzled source k (elements)
      __builtin_amdgcn_global_load_lds(
          (const AS1 u32*)(A + (size_t)(row0 + r) * lda + kt + ks),
          (AS3 u32*)(&sA[(size_t)cbase * 8]), 16, 0, 0);
      __builtin_amdgcn_global_load_lds(
          (const AS1 u32*)(Bm + (size_t)(col0 + r) * ldb + kt + ks),
          (AS3 u32*)(&sB[(size_t)cbase * 8]), 16, 0, 0);
    }
    __syncthreads();
#pragma unroll
    for (int kk = 0; kk < 2; ++kk) {
      bf16x8 fa[4], fb[4];
#pragma unroll
      for (int mi = 0; mi < 4; ++mi) {
        int rr = wr + mi * 16 + lr;
        int kb = (kk << 6) + lkb;
        fa[mi] = *(const bf16x8*)((const char*)sA + rr * 128 + (kb ^ ((rr & 7) << 4)));
      }
#pragma unroll
      for (int ni = 0; ni < 4; ++ni) {
        int rr = wc + ni * 16 + lr;
        int kb = (kk << 6) + lkb;
        fb[ni] = *(const bf16x8*)((const char*)sB + rr * 128 + (kb ^ ((rr & 7) << 4)));
      }
#pragma unroll
      for (int mi = 0; mi < 4; ++mi)
#pragma unroll
        for (int ni = 0; ni < 4; ++ni)
          acc[mi][ni] = __builtin_amdgcn_mfma_f32_16x16x32_bf16(fa[mi], fb[ni], acc[mi][ni], 0, 0, 0);
    }
    __syncthreads();
  }
#pragma unroll
  for (int ni = 0; ni < 4; ++ni) {
    int col = col0 + wc + ni * 16 + lr;
    float bv = bias[col];
#pragma unroll
    for (int mi = 0; mi < 4; ++mi) {
      int rb = row0 + wr + mi * 16 + ((lane >> 4) << 2);
#pragma unroll
      for (int r = 0; r < 4; ++r)
        C[(size_t)(rb + r) * ldc + col] = acc[mi][ni][r] + bv;
    }
  }
}

// ---------- persistent LSTM: 32 workgroups x 1 wave, W_hh in registers ----------
// wave w owns units u0=w*16..+16, all 4 gates; M dim = 16 batches.
__global__ __launch_bounds__(64, 1) void k_lstm(
    const float* __restrict__ xz,    // [2048][2048]  row = b*128+t
    const u16* __restrict__ Whh,     // [2048][512] bf16
    const float* __restrict__ c0,    // [16][512]
    const float* __restrict__ bhh,   // [2048]
    u16* __restrict__ hbuf,          // [2][16][512] bf16
    float* __restrict__ dec,         // [2048][512] f32
    u16* __restrict__ catb,          // [2048][1024] bf16 (cols 0..511)
    int* __restrict__ cnt) {         // [128] arrival counters
  const int w = blockIdx.x, lane = threadIdx.x;
  const int u = (w << 4) + (lane & 15);      // unit (N index)
  const int kof = (lane >> 4) << 3;          // k element offset
  const int bq = (lane >> 4) << 2;           // first batch of this lane's acc rows

  bf16x8 wf[4][16];
#pragma unroll
  for (int g = 0; g < 4; ++g)
#pragma unroll
    for (int kk = 0; kk < 16; ++kk)
      wf[g][kk] = *(const bf16x8*)(Whh + (size_t)(g * 512 + u) * 512 + kk * 32 + kof);

  float cst[4], bh[4];
#pragma unroll
  for (int r = 0; r < 4; ++r) cst[r] = c0[(bq + r) * 512 + u];
#pragma unroll
  for (int g = 0; g < 4; ++g) bh[g] = bhh[g * 512 + u];

  for (int t = 0; t < 128; ++t) {
    const u16* h = hbuf + (t & 1) * 8192;
    u16* hn = hbuf + ((t & 1) ^ 1) * 8192;

    float xzv[4][4];
#pragma unroll
    for (int r = 0; r < 4; ++r)
#pragma unroll
      for (int g = 0; g < 4; ++g)
        xzv[g][r] = xz[(size_t)((bq + r) * 128 + t) * 2048 + g * 512 + u];

    f32x4 acc[4];
#pragma unroll
    for (int g = 0; g < 4; ++g) acc[g] = f32x4{0.f, 0.f, 0.f, 0.f};
#pragma unroll
    for (int kk = 0; kk < 16; ++kk) {
      bf16x8 af = *(const bf16x8*)(h + (lane & 15) * 512 + kk * 32 + kof);
#pragma unroll
      for (int g = 0; g < 4; ++g)
        acc[g] = __builtin_amdgcn_mfma_f32_16x16x32_bf16(af, wf[g][kk], acc[g], 0, 0, 0);
    }
#pragma unroll
    for (int r = 0; r < 4; ++r) {
      float zi = acc[0][r] + xzv[0][r] + bh[0];
      float zf = acc[1][r] + xzv[1][r] + bh[1];
      float zg = acc[2][r] + xzv[2][r] + bh[2];
      float zo = acc[3][r] + xzv[3][r] + bh[3];
      float ig = 1.f / (1.f + __expf(-zi));
      float fg = 1.f / (1.f + __expf(-zf));
      float gg = tanhf(zg);
      float og = 1.f / (1.f + __expf(-zo));
      float c = fg * cst[r] + ig * gg;
      cst[r] = c;
      float hv = og * tanhf(c);
      int row = (bq + r) * 128 + t;
      dec[(size_t)row * 512 + u] = hv;
      u16 hb = f2bf(hv);
      catb[(size_t)row * 1024 + u] = hb;
      hn[(bq + r) * 512 + u] = hb;
    }
    // cross-workgroup step barrier (device scope)
    __threadfence();
    if (lane == 0) {
      __hip_atomic_fetch_add(cnt + t, 1, __ATOMIC_RELAXED, __HIP_MEMORY_SCOPE_AGENT);
      while (__hip_atomic_load(cnt + t, __ATOMIC_RELAXED, __HIP_MEMORY_SCOPE_AGENT) < 32)
        __builtin_amdgcn_s_sleep(2);
    }
    __threadfence();
  }
}

// ---------- fused attention (f32): scores -> softmax -> ctx -> cat[:,512:1024] ----------
__global__ __launch_bounds__(512) void k_attn(
    const float* __restrict__ dec,   // [2048][512]
    const float* __restrict__ enc,   // [16][128][512]
    u16* __restrict__ catb) {        // [2048][1024]
  __shared__ float decs[8][512];
  __shared__ float sc[8][128];
  __shared__ float dist[8][128];
  const int b = blockIdx.y, t0 = blockIdx.x << 3;
  const int tid = threadIdx.x, wv = tid >> 6, lane = tid & 63;

#pragma unroll
  for (int i = 0; i < 8; ++i) {
    int idx = tid + (i << 9);
    int rr = idx >> 9, cc = idx & 511;
    decs[rr][cc] = dec[(size_t)(b * 128 + t0 + rr) * 512 + cc];
  }
  __syncthreads();

  const int k0 = lane << 3;
  for (int si = 0; si < 16; ++si) {
    int s = (wv << 4) + si;
    const float* e = enc + (size_t)(b * 128 + s) * 512;
    float4 e0 = *(const float4*)(e + k0);
    float4 e1 = *(const float4*)(e + k0 + 4);
    float a[8];
#pragma unroll
    for (int t8 = 0; t8 < 8; ++t8) {
      const float* d = &decs[t8][k0];
      float4 d0 = *(const float4*)d;
      float4 d1 = *(const float4*)(d + 4);
      a[t8] = e0.x * d0.x + e0.y * d0.y + e0.z * d0.z + e0.w * d0.w +
              e1.x * d1.x + e1.y * d1.y + e1.z * d1.z + e1.w * d1.w;
    }
#pragma unroll
    for (int t8 = 0; t8 < 8; ++t8) {
      float v = a[t8];
#pragma unroll
      for (int off = 32; off; off >>= 1) v += __shfl_down(v, off);
      if (lane == 0) sc[t8][s] = v;
    }
  }
  __syncthreads();

  {  // softmax: wave wv handles row wv
    float v0 = sc[wv][lane], v1 = sc[wv][lane + 64];
    float m = fmaxf(v0, v1);
#pragma unroll
    for (int off = 32; off; off >>= 1) m = fmaxf(m, __shfl_xor(m, off));
    float e0 = __expf(v0 - m), e1 = __expf(v1 - m);
    float ssum = e0 + e1;
#pragma unroll
    for (int off = 32; off; off >>= 1) ssum += __shfl_xor(ssum, off);
    float inv = 1.f / ssum;
    dist[wv][lane] = e0 * inv;
    dist[wv][lane + 64] = e1 * inv;
  }
  __syncthreads();

  float a[8] = {0.f, 0.f, 0.f, 0.f, 0.f, 0.f, 0.f, 0.f};
  const float* eb = enc + (size_t)b * 128 * 512 + tid;
  for (int s = 0; s < 128; ++s) {
    float e = eb[(size_t)s * 512];
#pragma unroll
    for (int t8 = 0; t8 < 8; ++t8) a[t8] += dist[t8][s] * e;
  }
#pragma unroll
  for (int t8 = 0; t8 < 8; ++t8)
    catb[(size_t)(b * 128 + t0 + t8) * 1024 + 512 + tid] = f2bf(a[t8]);
}

// ---------- launcher ----------
extern "C" void kernel_launch(void* const* d_in, const int* in_sizes, int n_in,
                              void* d_out, int out_size, void* d_ws, size_t ws_size,
                              hipStream_t stream) {
  const int* indices = (const int*)d_in[0];
  const float* enc   = (const float*)d_in[1];
  const float* h0    = (const float*)d_in[2];
  const float* c0    = (const float*)d_in[3];
  const float* emb   = (const float*)d_in[4];
  const float* Wih_f = (const float*)d_in[5];
  const float* Whh_f = (const float*)d_in[6];
  const float* bih   = (const float*)d_in[7];
  const float* bhh   = (const float*)d_in[8];
  const float* Wout_f= (const float*)d_in[9];
  const float* bout  = (const float*)d_in[10];

  char* ws = (char*)d_ws;
  size_t off = 0;
  auto alloc = [&](size_t bytes) {
    void* p = ws + off;
    off += (bytes + 255) & ~(size_t)255;
    return p;
  };
  u16* Wih   = (u16*)alloc(2048ull * 512 * 2);
  u16* Whh   = (u16*)alloc(2048ull * 512 * 2);
  u16* Wout  = (u16*)alloc(32000ull * 1024 * 2);
  u16* xb    = (u16*)alloc(2048ull * 512 * 2);
  float* xz  = (float*)alloc(2048ull * 2048 * 4);
  u16* hbuf  = (u16*)alloc(2ull * 16 * 512 * 2);
  float* dec = (float*)alloc(2048ull * 512 * 4);
  u16* catb  = (u16*)alloc(2048ull * 1024 * 2);
  int* cnt   = (int*)alloc(512);
  (void)ws_size; (void)in_sizes; (void)n_in; (void)out_size;

  hipMemsetAsync(cnt, 0, 512, stream);
  k_conv4<<<dim3((262144 + 255) / 256), 256, 0, stream>>>((const float4*)Wih_f, (u16x4*)Wih, 262144);
  k_conv4<<<dim3((262144 + 255) / 256), 256, 0, stream>>>((const float4*)Whh_f, (u16x4*)Whh, 262144);
  k_conv4<<<dim3((8192000 + 255) / 256), 256, 0, stream>>>((const float4*)Wout_f, (u16x4*)Wout, 8192000);
  k_conv4<<<dim3((2048 + 255) / 256), 256, 0, stream>>>((const float4*)h0, (u16x4*)hbuf, 2048);
  k_gather<<<dim3(2048), 128, 0, stream>>>(indices, emb, xb);
  // xz = x @ W_ih^T + b_ih : M=2048 N=2048 K=512
  k_gemm_bt<<<dim3(16, 16), 256, 0, stream>>>(xb, 512, Wih, 512, bih, xz, 2048, 512);
  k_lstm<<<dim3(32), 64, 0, stream>>>(xz, Whh, c0, bhh, hbuf, dec, catb, cnt);
  k_attn<<<dim3(16, 16), 512, 0, stream>>>(dec, enc, catb);
  // out = cat @ W_out^T + b_out : M=2048 N=32000 K=1024
  k_gemm_bt<<<dim3(16, 250), 256, 0, stream>>>(catb, 1024, Wout, 1024, bout, (float*)d_out, 32000, 1024);
}